// Round 1
// baseline (1509.880 us; speedup 1.0000x reference)
//
#include <hip/hip_runtime.h>

// aggregation_custom_12695923327642 — round 3: atomic-free via counting sort.
//
// Pipeline (when ws_size permits, ~6.8 MB needed):
//   1. hist_kernel:    hist[node]++ over edges                (int atomics, L2)
//   2. scan_kernel:    exclusive scan -> offsets (+cursor)    (1 block)
//   3. scatter_kernel: sorted[atomicAdd(cursor[idx])] = e     (int atomics)
//   4. agg_sorted:     one WAVE per NODE: gather its edges in 16-edge chunks,
//                      verified MFMA gate tile, accumulate out[node][128] in
//                      registers, shfl_xor cross-quad reduce, ONE plain store.
//   => 204.8M f32 device atomics -> 0.  ~3.2M int atomics remain.
//
// Fallback (ws too small): previous harness-verified atomic kernel, unchanged.

#define D   128
#define PD  64
#define EPW 16          // edges per wave-tile / chunk
#define RS  132         // padded LDS row stride (f32) — 132%32=4 banks shift/row

typedef float  f32x4  __attribute__((ext_vector_type(4)));
typedef __bf16 bf16x8 __attribute__((ext_vector_type(8)));

static __device__ __forceinline__ float clamp01(float v) {
    return fminf(fmaxf(v, 0.0f), 1.0f);   // v_med3_f32
}

// ---------------------------------------------------------------------------
// 1. histogram
// ---------------------------------------------------------------------------
__global__ void hist_kernel(const int* __restrict__ index,
                            int* __restrict__ hist, int E)
{
    const int stride = gridDim.x * blockDim.x;
    for (int e = blockIdx.x * blockDim.x + threadIdx.x; e < E; e += stride)
        atomicAdd(&hist[index[e]], 1);
}

// ---------------------------------------------------------------------------
// 2. exclusive scan over Np1 = N+1 entries (hist[N]=0 -> offsets[N]=E).
//    Single block, 1024 threads, each owns a contiguous range.
// ---------------------------------------------------------------------------
__global__ void scan_kernel(int* hist, int* cursor, int Np1)
{
    __shared__ int s[1024];
    const int t     = threadIdx.x;
    const int chunk = (Np1 + 1023) / 1024;
    const int lo    = t * chunk;
    const int hi    = (lo + chunk < Np1) ? (lo + chunk) : Np1;

    int sum = 0;
    for (int i = lo; i < hi; ++i) sum += hist[i];
    s[t] = sum;
    __syncthreads();
    for (int off = 1; off < 1024; off <<= 1) {
        int v = (t >= off) ? s[t - off] : 0;
        __syncthreads();
        s[t] += v;
        __syncthreads();
    }
    int run = s[t] - sum;                  // exclusive base for this range
    for (int i = lo; i < hi; ++i) {
        const int c = hist[i];
        hist[i]   = run;                   // hist becomes exclusive offsets
        cursor[i] = run;                   // scatter cursor copy
        run += c;
    }
}

// ---------------------------------------------------------------------------
// 3. scatter edge ids into node buckets
// ---------------------------------------------------------------------------
__global__ void scatter_kernel(const int* __restrict__ index,
                               int* __restrict__ cursor,
                               int* __restrict__ sorted, int E)
{
    const int stride = gridDim.x * blockDim.x;
    for (int e = blockIdx.x * blockDim.x + threadIdx.x; e < E; e += stride) {
        const int n   = index[e];
        const int pos = atomicAdd(&cursor[n], 1);
        sorted[pos] = e;
    }
}

// ---------------------------------------------------------------------------
// 4. one wave per node: gather -> MFMA gates -> register-accumulate -> store
// ---------------------------------------------------------------------------
__global__ __launch_bounds__(256, 3) void agg_sorted_kernel(
    const float* __restrict__ x,
    const float* __restrict__ W,
    const float* __restrict__ lp_ptr,
    const int*  __restrict__ sorted,
    const int*  __restrict__ offsets,
    float* __restrict__ out,
    int N)
{
    const int tid  = threadIdx.x;
    const int wave = tid >> 6;
    const int lane = tid & 63;
    const int q    = lane >> 4;     // quad 0..3
    const int c    = lane & 15;

    __shared__ float shx_all[4][EPW * RS];
    float* shx = shx_all[wave];

    // ---- B-frags: B[k][n] = W[o=n][d=k]; lane holds n=c, k=ks*32+q*8+j ----
    bf16x8 bfrag[8][2];
    #pragma unroll
    for (int nt = 0; nt < 8; ++nt) {
        #pragma unroll
        for (int ks = 0; ks < 2; ++ks) {
            const float* wp = W + (nt * 16 + c) * PD + ks * 32 + q * 8;
            f32x4 w0 = *(const f32x4*)(wp);
            f32x4 w1 = *(const f32x4*)(wp + 4);
            bf16x8 f;
            f[0] = (__bf16)w0[0]; f[1] = (__bf16)w0[1];
            f[2] = (__bf16)w0[2]; f[3] = (__bf16)w0[3];
            f[4] = (__bf16)w1[0]; f[5] = (__bf16)w1[1];
            f[6] = (__bf16)w1[2]; f[7] = (__bf16)w1[3];
            bfrag[nt][ks] = f;
        }
    }

    const float lp = fabsf(lp_ptr[0]);

    const int totalWaves = gridDim.x * 4;
    for (int node = blockIdx.x * 4 + wave; node < N; node += totalWaves) {
        const int beg = offsets[node];
        const int end = offsets[node + 1];

        float acc8[8];
        #pragma unroll
        for (int k = 0; k < 8; ++k) acc8[k] = 0.0f;

        for (int base = beg; base < end; base += EPW) {
            const int rem = (end - base < EPW) ? (end - base) : EPW;

            // edge ids for this chunk, broadcast via shfl (no LDS needed)
            int myid = 0;
            if (lane < rem) myid = sorted[base + lane];

            // ---- stage gathered x tile: 16 edges x 128 f32, padded rows ----
            #pragma unroll
            for (int i = 0; i < 8; ++i) {
                const int v4   = lane + i * 64;
                const int eL   = v4 >> 5;      // 32 float4 per edge
                const int col4 = v4 & 31;
                const int eid  = __shfl(myid, eL);
                float4 val = make_float4(0.f, 0.f, 0.f, 0.f);
                if (eL < rem)
                    val = *(const float4*)(x + (size_t)eid * D + col4 * 4);
                *(float4*)&shx[eL * RS + col4 * 4] = val;
            }
            // same wave produces & consumes LDS — lgkmcnt ordering suffices

            #pragma unroll
            for (int mt = 0; mt < 2; ++mt) {
                // A-frags: A[m=c][k=ks*32+q*8+j] = e1[row>>1][row&1][k]
                const int rowl = mt * 16 + c;
                const int el   = rowl >> 1;
                const int p    = rowl & 1;
                bf16x8 afrag[2];
                #pragma unroll
                for (int ks = 0; ks < 2; ++ks) {
                    const float* ap = &shx[el * RS + p * PD + ks * 32 + q * 8];
                    f32x4 a0 = *(const f32x4*)(ap);
                    f32x4 a1 = *(const f32x4*)(ap + 4);
                    bf16x8 f;
                    f[0] = (__bf16)a0[0]; f[1] = (__bf16)a0[1];
                    f[2] = (__bf16)a0[2]; f[3] = (__bf16)a0[3];
                    f[4] = (__bf16)a1[0]; f[5] = (__bf16)a1[1];
                    f[6] = (__bf16)a1[2]; f[7] = (__bf16)a1[3];
                    afrag[ks] = f;
                }

                f32x4 acc[8];
                #pragma unroll
                for (int nt = 0; nt < 8; ++nt) {
                    acc[nt] = (f32x4){0.f, 0.f, 0.f, 0.f};
                    acc[nt] = __builtin_amdgcn_mfma_f32_16x16x32_bf16(
                                  afrag[0], bfrag[nt][0], acc[nt], 0, 0, 0);
                    acc[nt] = __builtin_amdgcn_mfma_f32_16x16x32_bf16(
                                  afrag[1], bfrag[nt][1], acc[nt], 0, 0, 0);
                }

                // ---- combine into per-node register accumulator ----
                // C-layout: col=c, row=q*4+reg -> reg0,1 = edge eAl (p=0,1);
                // reg2,3 = edge eBl. Invalid edges staged as 0 -> contribute 0.
                const int eAl = mt * 8 + q * 2;
                const int eBl = eAl + 1;

                #pragma unroll
                for (int dg = 0; dg < 4; ++dg) {
                    const int d = dg * 16 + c;
                    const float aA0 = shx[eAl * RS + d];        // e1[eA][0][d]
                    const float aA1 = shx[eAl * RS + 64 + d];   // e1[eA][1][d]
                    const float aB0 = shx[eBl * RS + d];
                    const float aB1 = shx[eBl * RS + 64 + d];

                    const f32x4 g0 = acc[dg];       // gate cols d      (chunk 0)
                    const f32x4 g1 = acc[dg + 4];   // gate cols 64+d   (chunk 1)
                    const float gA0 = clamp01(g0[0]), gA1 = clamp01(g0[1]);
                    const float gB0 = clamp01(g0[2]), gB1 = clamp01(g0[3]);
                    const float hA0 = clamp01(g1[0]), hA1 = clamp01(g1[1]);
                    const float hB0 = clamp01(g1[2]), hB1 = clamp01(g1[3]);

                    const float vA0 = aA0 + lp * (aA0 * gA0 + aA1 * gA1);
                    const float vA1 = aA1 + lp * (aA0 * hA0 + aA1 * hA1);
                    const float vB0 = aB0 + lp * (aB0 * gB0 + aB1 * gB1);
                    const float vB1 = aB1 + lp * (aB0 * hB0 + aB1 * hB1);

                    acc8[dg * 2]     += vA0 + vB0;   // dim d
                    acc8[dg * 2 + 1] += vA1 + vB1;   // dim 64+d
                }
            }
        }

        // ---- cross-quad reduce (lanes sharing c across q=0..3) ----
        #pragma unroll
        for (int k = 0; k < 8; ++k) {
            float v = acc8[k];
            v += __shfl_xor(v, 16);
            v += __shfl_xor(v, 32);
            acc8[k] = v;
        }

        // ---- single plain store of this node's 128 floats ----
        if (lane < 16) {
            float* op = out + (size_t)node * D + lane;   // c == lane here
            #pragma unroll
            for (int dg = 0; dg < 4; ++dg) {
                op[dg * 16]      = acc8[dg * 2];
                op[64 + dg * 16] = acc8[dg * 2 + 1];
            }
        }
    }
}

// ---------------------------------------------------------------------------
// Fallback: previous harness-verified atomic kernel (unchanged)
// ---------------------------------------------------------------------------
__global__ __launch_bounds__(256, 3) void agg_mfma_kernel(
    const float* __restrict__ x,
    const float* __restrict__ W,
    const float* __restrict__ lp_ptr,
    const int*  __restrict__ index,
    float* __restrict__ out,
    int E, int nTiles)
{
    const int tid  = threadIdx.x;
    const int wave = tid >> 6;
    const int lane = tid & 63;
    const int q    = lane >> 4;
    const int c    = lane & 15;

    __shared__ float shx_all[4][EPW * RS];
    __shared__ int   shidx_all[4][EPW];
    float* shx   = shx_all[wave];
    int*   shidx = shidx_all[wave];

    bf16x8 bfrag[8][2];
    #pragma unroll
    for (int nt = 0; nt < 8; ++nt) {
        #pragma unroll
        for (int ks = 0; ks < 2; ++ks) {
            const float* wp = W + (nt * 16 + c) * PD + ks * 32 + q * 8;
            f32x4 w0 = *(const f32x4*)(wp);
            f32x4 w1 = *(const f32x4*)(wp + 4);
            bf16x8 f;
            f[0] = (__bf16)w0[0]; f[1] = (__bf16)w0[1];
            f[2] = (__bf16)w0[2]; f[3] = (__bf16)w0[3];
            f[4] = (__bf16)w1[0]; f[5] = (__bf16)w1[1];
            f[6] = (__bf16)w1[2]; f[7] = (__bf16)w1[3];
            bfrag[nt][ks] = f;
        }
    }

    const float lp = fabsf(lp_ptr[0]);

    const int waveStride = gridDim.x * 4;
    for (int t = blockIdx.x * 4 + wave; t < nTiles; t += waveStride) {
        const long long e0 = (long long)t * EPW;
        const int remEdges = (int)((E - e0) < EPW ? (E - e0) : EPW);
        const int validV4  = remEdges * 32;

        const float4* xg = (const float4*)(x + e0 * D);
        #pragma unroll
        for (int i = 0; i < 8; ++i) {
            const int v4 = lane + i * 64;
            float4 val = make_float4(0.f, 0.f, 0.f, 0.f);
            if (v4 < validV4) val = xg[v4];
            const int g4   = v4 * 4;
            const int edge = g4 >> 7;
            const int col  = g4 & 127;
            *(float4*)&shx[edge * RS + col] = val;
        }
        if (lane < EPW)
            shidx[lane] = (lane < remEdges) ? index[e0 + lane] : 0;

        #pragma unroll
        for (int mt = 0; mt < 2; ++mt) {
            const int rowl = mt * 16 + c;
            const int el   = rowl >> 1;
            const int p    = rowl & 1;
            bf16x8 afrag[2];
            #pragma unroll
            for (int ks = 0; ks < 2; ++ks) {
                const float* ap = &shx[el * RS + p * PD + ks * 32 + q * 8];
                f32x4 a0 = *(const f32x4*)(ap);
                f32x4 a1 = *(const f32x4*)(ap + 4);
                bf16x8 f;
                f[0] = (__bf16)a0[0]; f[1] = (__bf16)a0[1];
                f[2] = (__bf16)a0[2]; f[3] = (__bf16)a0[3];
                f[4] = (__bf16)a1[0]; f[5] = (__bf16)a1[1];
                f[6] = (__bf16)a1[2]; f[7] = (__bf16)a1[3];
                afrag[ks] = f;
            }

            f32x4 acc[8];
            #pragma unroll
            for (int nt = 0; nt < 8; ++nt) {
                acc[nt] = (f32x4){0.f, 0.f, 0.f, 0.f};
                acc[nt] = __builtin_amdgcn_mfma_f32_16x16x32_bf16(
                              afrag[0], bfrag[nt][0], acc[nt], 0, 0, 0);
                acc[nt] = __builtin_amdgcn_mfma_f32_16x16x32_bf16(
                              afrag[1], bfrag[nt][1], acc[nt], 0, 0, 0);
            }

            const int  eAl   = mt * 8 + q * 2;
            const int  eBl   = eAl + 1;
            const int  nodeA = shidx[eAl];
            const int  nodeB = shidx[eBl];
            const bool okA   = (e0 + eAl) < E;
            const bool okB   = (e0 + eBl) < E;
            float* outA = out + (long long)nodeA * D + c;
            float* outB = out + (long long)nodeB * D + c;

            #pragma unroll
            for (int dg = 0; dg < 4; ++dg) {
                const int d = dg * 16 + c;
                const float aA0 = shx[eAl * RS + d];
                const float aA1 = shx[eAl * RS + 64 + d];
                const float aB0 = shx[eBl * RS + d];
                const float aB1 = shx[eBl * RS + 64 + d];

                const f32x4 g0 = acc[dg];
                const f32x4 g1 = acc[dg + 4];
                const float gA0 = clamp01(g0[0]), gA1 = clamp01(g0[1]);
                const float gB0 = clamp01(g0[2]), gB1 = clamp01(g0[3]);
                const float hA0 = clamp01(g1[0]), hA1 = clamp01(g1[1]);
                const float hB0 = clamp01(g1[2]), hB1 = clamp01(g1[3]);

                const float vA0 = aA0 + lp * (aA0 * gA0 + aA1 * gA1);
                const float vA1 = aA1 + lp * (aA0 * hA0 + aA1 * hA1);
                const float vB0 = aB0 + lp * (aB0 * gB0 + aB1 * gB1);
                const float vB1 = aB1 + lp * (aB0 * hB0 + aB1 * hB1);

                if (okA) {
                    atomicAdd(outA + dg * 16,      vA0);
                    atomicAdd(outA + 64 + dg * 16, vA1);
                }
                if (okB) {
                    atomicAdd(outB + dg * 16,      vB0);
                    atomicAdd(outB + 64 + dg * 16, vB1);
                }
            }
        }
    }
}

extern "C" void kernel_launch(void* const* d_in, const int* in_sizes, int n_in,
                              void* d_out, int out_size, void* d_ws, size_t ws_size,
                              hipStream_t stream) {
    const float* x     = (const float*)d_in[0];
    const float* W     = (const float*)d_in[1];
    const float* lp    = (const float*)d_in[2];
    const int*   index = (const int*)d_in[3];
    float*       out   = (float*)d_out;

    const int E = in_sizes[0] / D;
    const int N = out_size / D;

    const size_t need = ((size_t)(N + 1) * 2 + (size_t)E) * sizeof(int);

    if (d_ws != nullptr && ws_size >= need) {
        // ---- sorted, atomic-free path ----
        int* hist   = (int*)d_ws;          // N+1 ints -> exclusive offsets
        int* cursor = hist + (N + 1);      // N+1 ints
        int* sorted = cursor + (N + 1);    // E ints

        hipMemsetAsync(hist, 0, (size_t)(N + 1) * sizeof(int), stream);
        hist_kernel<<<2048, 256, 0, stream>>>(index, hist, E);
        scan_kernel<<<1, 1024, 0, stream>>>(hist, cursor, N + 1);
        scatter_kernel<<<2048, 256, 0, stream>>>(index, cursor, sorted, E);

        int grid = (N + 3) / 4;
        if (grid > 2560) grid = 2560;
        // every node is written exactly once by its owning wave -> no memset of out
        agg_sorted_kernel<<<grid, 256, 0, stream>>>(x, W, lp, sorted, hist, out, N);
    } else {
        // ---- fallback: verified atomic path ----
        const int nTiles = (E + EPW - 1) / EPW;
        hipMemsetAsync(d_out, 0, (size_t)out_size * sizeof(float), stream);
        int grid = (nTiles + 3) / 4;
        if (grid > 2560) grid = 2560;
        agg_mfma_kernel<<<grid, 256, 0, stream>>>(x, W, lp, index, out, E, nTiles);
    }
}